// Round 3
// 367.574 us; speedup vs baseline: 1.2090x; 1.2090x over previous
//
#include <hip/hip_runtime.h>
#include <hip/hip_bf16.h>

// Problem constants (BS=1)
#define CAMS   6
#define NQ     6400
#define EMBED  256
#define HEADS  8
#define LEVELS 4
#define POINTS 8
#define DEPTH  4
#define DH     32
#define FLEN   14960
#define MV     (FLEN * CAMS)   // 89760 rows for v-projection

__constant__ int c_LW[4] = {176, 88, 44, 22};
__constant__ int c_LH[4] = {64, 32, 16, 8};
__constant__ int c_LS[4] = {0, 11264, 14080, 14784};

typedef __bf16 bf16x8 __attribute__((ext_vector_type(8)));
typedef float  f32x4  __attribute__((ext_vector_type(4)));

__device__ __forceinline__ ushort f2bf(float x) {
    __hip_bfloat16 h = __float2bfloat16(x);
    return *(ushort*)&h;
}
__device__ __forceinline__ float bflo(unsigned u) { return __uint_as_float(u << 16); }
__device__ __forceinline__ float bfhi(unsigned u) { return __uint_as_float(u & 0xffff0000u); }

#define LSTRIDE 40

// ---------------------------------------------------------------------------
// bf16 MFMA GEMM body, software-pipelined (regs prefetch next K-tile under MFMA)
// MODE 0: C = A@W + b                  (v-proj; OUT==1 -> bf16 in [cam][h][pix][32] layout)
// MODE 1: C = (A+A2)@W + b             (query+query_pos projections, fp32 out)
// MODE 3: C = A@W + b + resid          (output projection, fp32 out)
// ---------------------------------------------------------------------------
template <int MODE, int OUT>
__device__ __forceinline__ void gemm_body(ushort* sA, ushort* sB,
                                          const float* __restrict__ A,
                                          const float* __restrict__ A2,
                                          const float* __restrict__ W, int ldw,
                                          const float* __restrict__ bias,
                                          const float* __restrict__ resid,
                                          void* __restrict__ Cout, int ldc, int M,
                                          int bx, int by) {
    const int t = threadIdx.x;
    const int wave = t >> 6;
    const int lane = t & 63;
    const int wm = wave & 1, wn = wave >> 1;
    const int lane15 = lane & 15;
    const int laneq = lane >> 4;
    const int row0 = bx * 128;
    const int col0 = by * 128;

    f32x4 acc[4][4] = {};

    const int a_m = t >> 3;
    const int a_k = (t & 7) * 4;
    const int b_n = t & 127;
    const int b_k = (t >> 7) * 4;

    float4 aR[4], wR[4];

    // prologue: issue loads for k0 = 0
    #pragma unroll
    for (int p = 0; p < 4; ++p) {
        int gm = row0 + a_m + p * 32;
        if (gm >= M) gm = M - 1;
        aR[p] = *(const float4*)(A + (size_t)gm * 256 + a_k);
    }
    #pragma unroll
    for (int p = 0; p < 4; ++p) {
        const int k = b_k + p * 8;
        const float* wp = W + (size_t)k * ldw + col0 + b_n;
        wR[p] = make_float4(wp[0], wp[ldw], wp[2 * ldw], wp[3 * ldw]);
    }

    for (int k0 = 0; k0 < 256; k0 += 32) {
        // stage prefetched registers into LDS
        #pragma unroll
        for (int p = 0; p < 4; ++p) {
            const int m = a_m + p * 32;
            float4 a4 = aR[p];
            if (MODE == 1) {
                int gm = row0 + m;
                if (gm >= M) gm = M - 1;
                float4 b4 = *(const float4*)(A2 + (size_t)gm * 256 + k0 + a_k);
                a4.x += b4.x; a4.y += b4.y; a4.z += b4.z; a4.w += b4.w;
            }
            *(ushort4*)(&sA[m * LSTRIDE + a_k]) =
                make_ushort4(f2bf(a4.x), f2bf(a4.y), f2bf(a4.z), f2bf(a4.w));
        }
        #pragma unroll
        for (int p = 0; p < 4; ++p) {
            const int k = b_k + p * 8;
            *(ushort4*)(&sB[b_n * LSTRIDE + k]) =
                make_ushort4(f2bf(wR[p].x), f2bf(wR[p].y), f2bf(wR[p].z), f2bf(wR[p].w));
        }
        __syncthreads();

        // prefetch next K-tile; these loads complete under ds_read+MFMA+barrier
        if (k0 + 32 < 256) {
            #pragma unroll
            for (int p = 0; p < 4; ++p) {
                int gm = row0 + a_m + p * 32;
                if (gm >= M) gm = M - 1;
                aR[p] = *(const float4*)(A + (size_t)gm * 256 + k0 + 32 + a_k);
            }
            #pragma unroll
            for (int p = 0; p < 4; ++p) {
                const int k = b_k + p * 8;
                const float* wp = W + (size_t)(k0 + 32 + k) * ldw + col0 + b_n;
                wR[p] = make_float4(wp[0], wp[ldw], wp[2 * ldw], wp[3 * ldw]);
            }
        }

        bf16x8 af[4], bfr[4];
        #pragma unroll
        for (int i = 0; i < 4; ++i) {
            const int m = wm * 64 + i * 16 + lane15;
            af[i] = *(const bf16x8*)(&sA[m * LSTRIDE + laneq * 8]);
            const int n = wn * 64 + i * 16 + lane15;
            bfr[i] = *(const bf16x8*)(&sB[n * LSTRIDE + laneq * 8]);
        }
        #pragma unroll
        for (int i = 0; i < 4; ++i)
            #pragma unroll
            for (int j = 0; j < 4; ++j)
                acc[i][j] = __builtin_amdgcn_mfma_f32_16x16x32_bf16(af[i], bfr[j], acc[i][j], 0, 0, 0);
        __syncthreads();
    }

    #pragma unroll
    for (int j = 0; j < 4; ++j) {
        const int col = col0 + wn * 64 + j * 16 + lane15;
        const float bcol = bias[col];
        #pragma unroll
        for (int i = 0; i < 4; ++i) {
            #pragma unroll
            for (int r = 0; r < 4; ++r) {
                const int row = row0 + wm * 64 + i * 16 + laneq * 4 + r;
                if (row < M) {
                    float v = acc[i][j][r] + bcol;
                    if (OUT == 1) {
                        // scatter into [cam][head][pix][32ch] bf16 layout
                        const unsigned pix = ((unsigned)row * 43691u) >> 18;  // row/6 (exact for row<131072)
                        const unsigned cam = (unsigned)row - pix * 6u;
                        const int hh = col >> 5, ch = col & 31;
                        ((ushort*)Cout)[((size_t)(cam * 8 + hh) * FLEN + pix) * 32 + ch] = f2bf(v);
                    } else {
                        if (MODE == 3) v += resid[(size_t)row * 256 + col];
                        ((float*)Cout)[(size_t)row * ldc + col] = v;
                    }
                }
            }
        }
    }
}

// ---------------------------------------------------------------------------
// One launch for all three independent pre-GEMMs + bev_mask format detection:
//   blocks [0,1404)   : v-proj   (MV x 256) @ Wv  -> v_ws (bf16, cam/h/pix layout)
//   blocks [1404,1604): (q+pos)  (NQ x 512) @ Wso -> off_ws
//   blocks [1604,1704): (q+pos)  (NQ x 256) @ Waw -> aw_ws (raw logits)
//   block  1704       : scan first 153600 B of bev_mask -> flag (1=bool bytes,
//                       0=int32). Bool-byte packing sets upper bytes of 32-bit
//                       words; int32 0/1 values never do. (Scans only the
//                       minimum size valid for BOTH formats.)
// ---------------------------------------------------------------------------
__launch_bounds__(256)
__global__ void fused_pre_gemm(const float* __restrict__ value,
                               const float* __restrict__ query,
                               const float* __restrict__ query_pos,
                               const float* __restrict__ Wv,  const float* __restrict__ bv,
                               const float* __restrict__ Wso, const float* __restrict__ bso,
                               const float* __restrict__ Waw, const float* __restrict__ baw,
                               const void* __restrict__ bm,
                               ushort* __restrict__ v_ws,
                               float* __restrict__ off_ws,
                               float* __restrict__ aw_ws,
                               int* __restrict__ flag) {
    __shared__ ushort sA[128 * LSTRIDE];
    __shared__ ushort sB[128 * LSTRIDE];
    const int bid = blockIdx.x;
    if (bid < 1404) {
        gemm_body<0, 1>(sA, sB, value, nullptr, Wv, 256, bv, nullptr,
                        v_ws, 256, MV, bid >> 1, bid & 1);
    } else if (bid < 1604) {
        const int r = bid - 1404;
        gemm_body<1, 0>(sA, sB, query, query_pos, Wso, 512, bso, nullptr,
                        off_ws, 512, NQ, r >> 2, r & 3);
    } else if (bid < 1704) {
        const int r = bid - 1604;
        gemm_body<1, 0>(sA, sB, query, query_pos, Waw, 256, baw, nullptr,
                        aw_ws, 256, NQ, r >> 1, r & 1);
    } else {
        const int t = threadIdx.x;
        const uint4* p4 = (const uint4*)bm;
        unsigned acc = 0;
        for (int i = t; i < (CAMS * NQ * DEPTH) / 16; i += 256) {
            const uint4 w = p4[i];
            acc |= w.x | w.y | w.z | w.w;
        }
        #pragma unroll
        for (int off = 32; off >= 1; off >>= 1) acc |= __shfl_xor(acc, off);
        unsigned* sred = (unsigned*)sA;
        if ((t & 63) == 0) sred[t >> 6] = acc;
        __syncthreads();
        if (t == 0) {
            const unsigned a = sred[0] | sred[1] | sred[2] | sred[3];
            flag[0] = (a & 0xFFFFFF00u) ? 1 : 0;
        }
    }
}

__launch_bounds__(256)
__global__ void gemm_out_kernel(const float* __restrict__ slots,
                                const float* __restrict__ Wout,
                                const float* __restrict__ bout,
                                const float* __restrict__ query,
                                float* __restrict__ out) {
    __shared__ ushort sA[128 * LSTRIDE];
    __shared__ ushort sB[128 * LSTRIDE];
    const int bid = blockIdx.x;
    gemm_body<3, 0>(sA, sB, slots, nullptr, Wout, 256, bout, query,
                    out, 256, NQ, bid >> 1, bid & 1);
}

// ---------------------------------------------------------------------------
// Deformable sampling — folds bev_mask decode, softmax, and 1/count scaling.
// One block per query. Thread t = h*32 + e8*4 + ch8idx handles entries
// e = e8*4 + j (j=0..3, = depth j) of head h, channels ch8..ch8+7.
// v layout is [cam][head][pix][32ch] bf16 so bilinear x/x+1 corners are
// adjacent 64B chunks (shared 128B TCC lines).
// Mask format selected at runtime via flag (block-uniform branch).
// ---------------------------------------------------------------------------
__launch_bounds__(256)
__global__ void sample_kernel(const ushort* __restrict__ v,
                              const float* __restrict__ off_ws,
                              const float* __restrict__ aw_logit,
                              const float* __restrict__ rp,      // (CAMS,NQ,DEPTH,2)
                              const void* __restrict__ bm,
                              const int* __restrict__ flag,
                              float* __restrict__ slots) {
    const int q = blockIdx.x;
    const int t = threadIdx.x;
    const int h = t >> 5;
    const int e8 = (t >> 2) & 7;
    const int ch8 = (t & 3) * 8;
    const int l = e8 >> 1;
    const int ebase = h * 32 + e8 * 4;

    const int Wl = c_LW[l], Hl = c_LH[l], St = c_LS[l];
    const float fWl = (float)Wl, fHl = (float)Hl;

    // active-cam mask + count (uniform across block; L1-broadcast loads)
    const int fmt = *flag;
    int am = 0, cnt = 0;
    if (fmt == 1) {         // bool bytes: 4 bytes per (cam,q)
        #pragma unroll
        for (int cam = 0; cam < CAMS; ++cam) {
            const unsigned w = ((const unsigned*)bm)[cam * NQ + q];
            const int a = (w != 0u);
            am |= a << cam;
            cnt += a;
        }
    } else {                // int32: 16 bytes per (cam,q)
        #pragma unroll
        for (int cam = 0; cam < CAMS; ++cam) {
            const int4 w = ((const int4*)bm)[cam * NQ + q];
            const int a = ((w.x | w.y | w.z | w.w) != 0);
            am |= a << cam;
            cnt += a;
        }
    }
    const float invq = 1.0f / (float)(cnt > 0 ? cnt : 1);

    // softmax over the 32 (l,p) logits of this (q,h): lanes differing in e8
    const float4 lg = *(const float4*)(aw_logit + (size_t)q * 256 + ebase);
    float mx = fmaxf(fmaxf(lg.x, lg.y), fmaxf(lg.z, lg.w));
    mx = fmaxf(mx, __shfl_xor(mx, 4));
    mx = fmaxf(mx, __shfl_xor(mx, 8));
    mx = fmaxf(mx, __shfl_xor(mx, 16));
    const float e0 = expf(lg.x - mx), e1 = expf(lg.y - mx);
    const float e2 = expf(lg.z - mx), e3 = expf(lg.w - mx);
    float s = e0 + e1 + e2 + e3;
    s += __shfl_xor(s, 4);
    s += __shfl_xor(s, 8);
    s += __shfl_xor(s, 16);
    const float sc = invq / s;                 // fold 1/count into the weights
    const float awv[4] = {e0 * sc, e1 * sc, e2 * sc, e3 * sc};

    const float* ofp = off_ws + (size_t)q * 512 + ebase * 2;
    const float4 o01 = *(const float4*)(ofp);
    const float4 o23 = *(const float4*)(ofp + 4);
    const float offx[4] = {o01.x, o01.z, o23.x, o23.z};
    const float offy[4] = {o01.y, o01.w, o23.y, o23.w};

    float acc[8] = {};

    for (int cam = 0; cam < CAMS; ++cam) {
        if (!((am >> cam) & 1)) continue;   // uniform branch

        const int camhF = (cam * 8 + h) * FLEN + St;

        const float4 r01 = *(const float4*)(rp + (size_t)cam * (NQ * 8) + q * 8);
        const float4 r23 = *(const float4*)(rp + (size_t)cam * (NQ * 8) + q * 8 + 4);
        const float rx[4] = {r01.x, r01.z, r23.x, r23.z};
        const float ry[4] = {r01.y, r01.w, r23.y, r23.w};

        int   addr[16];
        float wgt[16];
        #pragma unroll
        for (int j = 0; j < 4; ++j) {
            const float x = fmaf(rx[j], fWl, offx[j]) - 0.5f;
            const float y = fmaf(ry[j], fHl, offy[j]) - 0.5f;
            const float x0f = floorf(x), y0f = floorf(y);
            const int x0 = (int)x0f, y0 = (int)y0f;
            const float fx = x - x0f, fy = y - y0f;
            const float wx0 = 1.f - fx, wy0 = 1.f - fy;
            #pragma unroll
            for (int c = 0; c < 4; ++c) {
                const int cx = x0 + (c & 1);
                const int cy = y0 + (c >> 1);
                const bool valid = ((unsigned)cx < (unsigned)Wl) & ((unsigned)cy < (unsigned)Hl);
                const int pixo = valid ? (cy * Wl + cx) : 0;
                addr[j * 4 + c] = ((camhF + pixo) << 5) + ch8;
                wgt[j * 4 + c] = valid
                    ? (((c & 1) ? fx : wx0) * ((c >> 1) ? fy : wy0) * awv[j])
                    : 0.f;
            }
        }
        #pragma unroll
        for (int i = 0; i < 16; ++i) {
            const uint4 u = *(const uint4*)(v + addr[i]);
            const float w = wgt[i];
            acc[0] = fmaf(w, bflo(u.x), acc[0]);
            acc[1] = fmaf(w, bfhi(u.x), acc[1]);
            acc[2] = fmaf(w, bflo(u.y), acc[2]);
            acc[3] = fmaf(w, bfhi(u.y), acc[3]);
            acc[4] = fmaf(w, bflo(u.z), acc[4]);
            acc[5] = fmaf(w, bfhi(u.z), acc[5]);
            acc[6] = fmaf(w, bflo(u.w), acc[6]);
            acc[7] = fmaf(w, bfhi(u.w), acc[7]);
        }
    }

    // reduce over the 8 e8-groups (lane bits 2..4 within each 32-lane h-group)
    #pragma unroll
    for (int i = 0; i < 8; ++i) {
        acc[i] += __shfl_xor(acc[i], 4);
        acc[i] += __shfl_xor(acc[i], 8);
        acc[i] += __shfl_xor(acc[i], 16);
    }
    slots[(size_t)q * 256 + h * 32 + ch8 + e8] = acc[e8];
}

// ---------------------------------------------------------------------------
extern "C" void kernel_launch(void* const* d_in, const int* in_sizes, int n_in,
                              void* d_out, int out_size, void* d_ws, size_t ws_size,
                              hipStream_t stream) {
    const float* query     = (const float*)d_in[0];
    // d_in[1] = key (unused by reference)
    const float* value     = (const float*)d_in[2];
    const float* query_pos = (const float*)d_in[3];
    const float* refpts    = (const float*)d_in[4];
    const void*  bev_mask  = d_in[5];
    const float* Wv   = (const float*)d_in[8];
    const float* bv   = (const float*)d_in[9];
    const float* Wso  = (const float*)d_in[10];
    const float* bso  = (const float*)d_in[11];
    const float* Waw  = (const float*)d_in[12];
    const float* baw  = (const float*)d_in[13];
    const float* Wout = (const float*)d_in[14];
    const float* bout = (const float*)d_in[15];
    float* out = (float*)d_out;

    // Workspace layout
    ushort* v_ws  = (ushort*)d_ws;                       // MV*256 bf16 = 45.96 MB
    float* off_ws = (float*)(v_ws + (size_t)MV * 256);   // NQ*512 fp32
    float* aw_ws  = off_ws + (size_t)NQ * 512;           // NQ*256 (raw logits)
    float* slots  = aw_ws + (size_t)NQ * 256;            // NQ*256
    int*   flag   = (int*)(slots + (size_t)NQ * 256);    // 1 int

    // all three pre-GEMMs + mask-format detection in one dispatch
    hipLaunchKernelGGL(fused_pre_gemm, dim3(1705), dim3(256), 0, stream,
                       value, query, query_pos, Wv, bv, Wso, bso, Waw, baw,
                       bev_mask, v_ws, off_ws, aw_ws, flag);

    // deformable sampling (mask decode + softmax + 1/count folded in)
    hipLaunchKernelGGL(sample_kernel, dim3(NQ), dim3(256), 0, stream,
                       v_ws, off_ws, aw_ws, refpts, bev_mask, flag, slots);

    // out = slots @ Wout + bout + query   (1/count already folded into sample)
    hipLaunchKernelGGL(gemm_out_kernel, dim3(100), dim3(256), 0, stream,
                       slots, Wout, bout, query, out);
}

// Round 4
// 355.893 us; speedup vs baseline: 1.2487x; 1.0328x over previous
//
#include <hip/hip_runtime.h>
#include <hip/hip_bf16.h>

// Problem constants (BS=1)
#define CAMS   6
#define NQ     6400
#define EMBED  256
#define HEADS  8
#define LEVELS 4
#define POINTS 8
#define DEPTH  4
#define DH     32
#define FLEN   14960
#define MV     (FLEN * CAMS)   // 89760 rows for v-projection
#define NCHUNK 2805            // MV / 32

__constant__ int c_LW[4] = {176, 88, 44, 22};
__constant__ int c_LH[4] = {64, 32, 16, 8};
__constant__ int c_LS[4] = {0, 11264, 14080, 14784};

typedef __bf16 bf16x8 __attribute__((ext_vector_type(8)));
typedef float  f32x4  __attribute__((ext_vector_type(4)));

__device__ __forceinline__ ushort f2bf(float x) {
    __hip_bfloat16 h = __float2bfloat16(x);
    return *(ushort*)&h;
}
__device__ __forceinline__ float bflo(unsigned u) { return __uint_as_float(u << 16); }
__device__ __forceinline__ float bfhi(unsigned u) { return __uint_as_float(u & 0xffff0000u); }

__device__ __forceinline__ bf16x8 pack8(float4 a, float4 b) {
    union { ushort u[8]; bf16x8 v; } r;
    r.u[0] = f2bf(a.x); r.u[1] = f2bf(a.y); r.u[2] = f2bf(a.z); r.u[3] = f2bf(a.w);
    r.u[4] = f2bf(b.x); r.u[5] = f2bf(b.y); r.u[6] = f2bf(b.z); r.u[7] = f2bf(b.w);
    return r.v;
}

#define LSTRIDE 40

// ---------------------------------------------------------------------------
// bf16 MFMA GEMM body (verified R3) — used for the small q-projections and
// the output projection.
// MODE 1: C = (A+A2)@W + b   (fp32 out)
// MODE 3: C = A@W + b + resid (fp32 out)
// ---------------------------------------------------------------------------
template <int MODE>
__device__ __forceinline__ void gemm_body(ushort* sA, ushort* sB,
                                          const float* __restrict__ A,
                                          const float* __restrict__ A2,
                                          const float* __restrict__ W, int ldw,
                                          const float* __restrict__ bias,
                                          const float* __restrict__ resid,
                                          float* __restrict__ Cout, int ldc, int M,
                                          int bx, int by) {
    const int t = threadIdx.x;
    const int wave = t >> 6;
    const int lane = t & 63;
    const int wm = wave & 1, wn = wave >> 1;
    const int lane15 = lane & 15;
    const int laneq = lane >> 4;
    const int row0 = bx * 128;
    const int col0 = by * 128;

    f32x4 acc[4][4] = {};

    const int a_m = t >> 3;
    const int a_k = (t & 7) * 4;
    const int b_n = t & 127;
    const int b_k = (t >> 7) * 4;

    float4 aR[4], wR[4];

    #pragma unroll
    for (int p = 0; p < 4; ++p) {
        int gm = row0 + a_m + p * 32;
        if (gm >= M) gm = M - 1;
        aR[p] = *(const float4*)(A + (size_t)gm * 256 + a_k);
    }
    #pragma unroll
    for (int p = 0; p < 4; ++p) {
        const int k = b_k + p * 8;
        const float* wp = W + (size_t)k * ldw + col0 + b_n;
        wR[p] = make_float4(wp[0], wp[ldw], wp[2 * ldw], wp[3 * ldw]);
    }

    for (int k0 = 0; k0 < 256; k0 += 32) {
        #pragma unroll
        for (int p = 0; p < 4; ++p) {
            const int m = a_m + p * 32;
            float4 a4 = aR[p];
            if (MODE == 1) {
                int gm = row0 + m;
                if (gm >= M) gm = M - 1;
                float4 b4 = *(const float4*)(A2 + (size_t)gm * 256 + k0 + a_k);
                a4.x += b4.x; a4.y += b4.y; a4.z += b4.z; a4.w += b4.w;
            }
            *(ushort4*)(&sA[m * LSTRIDE + a_k]) =
                make_ushort4(f2bf(a4.x), f2bf(a4.y), f2bf(a4.z), f2bf(a4.w));
        }
        #pragma unroll
        for (int p = 0; p < 4; ++p) {
            const int k = b_k + p * 8;
            *(ushort4*)(&sB[b_n * LSTRIDE + k]) =
                make_ushort4(f2bf(wR[p].x), f2bf(wR[p].y), f2bf(wR[p].z), f2bf(wR[p].w));
        }
        __syncthreads();

        if (k0 + 32 < 256) {
            #pragma unroll
            for (int p = 0; p < 4; ++p) {
                int gm = row0 + a_m + p * 32;
                if (gm >= M) gm = M - 1;
                aR[p] = *(const float4*)(A + (size_t)gm * 256 + k0 + 32 + a_k);
            }
            #pragma unroll
            for (int p = 0; p < 4; ++p) {
                const int k = b_k + p * 8;
                const float* wp = W + (size_t)(k0 + 32 + k) * ldw + col0 + b_n;
                wR[p] = make_float4(wp[0], wp[ldw], wp[2 * ldw], wp[3 * ldw]);
            }
        }

        bf16x8 af[4], bfr[4];
        #pragma unroll
        for (int i = 0; i < 4; ++i) {
            const int m = wm * 64 + i * 16 + lane15;
            af[i] = *(const bf16x8*)(&sA[m * LSTRIDE + laneq * 8]);
            const int n = wn * 64 + i * 16 + lane15;
            bfr[i] = *(const bf16x8*)(&sB[n * LSTRIDE + laneq * 8]);
        }
        #pragma unroll
        for (int i = 0; i < 4; ++i)
            #pragma unroll
            for (int j = 0; j < 4; ++j)
                acc[i][j] = __builtin_amdgcn_mfma_f32_16x16x32_bf16(af[i], bfr[j], acc[i][j], 0, 0, 0);
        __syncthreads();
    }

    #pragma unroll
    for (int j = 0; j < 4; ++j) {
        const int col = col0 + wn * 64 + j * 16 + lane15;
        const float bcol = bias[col];
        #pragma unroll
        for (int i = 0; i < 4; ++i) {
            #pragma unroll
            for (int r = 0; r < 4; ++r) {
                const int row = row0 + wm * 64 + i * 16 + laneq * 4 + r;
                if (row < M) {
                    float v = acc[i][j][r] + bcol;
                    if (MODE == 3) v += resid[(size_t)row * 256 + col];
                    Cout[(size_t)row * ldc + col] = v;
                }
            }
        }
    }
}

// ---------------------------------------------------------------------------
// W-stationary barrier-free v-projection.
// Full W (256x256) staged ONCE to LDS as bf16, col-major [n][k] with XOR
// swizzle (k ^ ((n&7)<<3)) for conflict-minimal ds_read_b128 B-frags.
// Then each wave independently streams 32-row chunks of A: preload whole
// chunk's A to regs (16 KB in flight -> HBM saturated by ILP), 128 MFMA,
// scatter-store bf16 to v_ws[cam][head][pix][32ch]. No barriers in the loop.
// ---------------------------------------------------------------------------
__device__ __forceinline__ void vproj_body(ushort* sW,
                                           const float* __restrict__ A,
                                           const float* __restrict__ W,
                                           const float* __restrict__ bias,
                                           ushort* __restrict__ v_ws,
                                           int bid) {
    const int t = threadIdx.x;

    // ---- stage W: thread t owns column n=t; reads 4 consecutive k per round
    {
        const int n = t;
        const int xr = (n & 7) << 3;
        #pragma unroll 8
        for (int r = 0; r < 64; ++r) {
            const int k4 = r * 4;
            const float w0 = W[(size_t)(k4 + 0) * 256 + n];
            const float w1 = W[(size_t)(k4 + 1) * 256 + n];
            const float w2 = W[(size_t)(k4 + 2) * 256 + n];
            const float w3 = W[(size_t)(k4 + 3) * 256 + n];
            *(ushort4*)(&sW[n * 256 + (k4 ^ xr)]) =
                make_ushort4(f2bf(w0), f2bf(w1), f2bf(w2), f2bf(w3));
        }
    }
    __syncthreads();

    const int wave = t >> 6, lane = t & 63;
    const int lane15 = lane & 15, laneq = lane >> 4;

    // per-wave bias for the 16 column tiles (chunk-independent)
    float bcol[16];
    #pragma unroll
    for (int nt = 0; nt < 16; ++nt) bcol[nt] = bias[nt * 16 + lane15];

    const int g = bid * 4 + wave;          // wave-global id in [0,1024)
    for (int c = g; c < NCHUNK; c += 1024) {
        const int rowbase = c * 32;
        const float* ap0 = A + (size_t)(rowbase + lane15) * 256 + laneq * 8;
        const float* ap1 = ap0 + 16 * 256;

        // preload the whole chunk's A (32 rows x 256 k fp32) -> 16 dwordx4
        float4 a[2][8][2];
        #pragma unroll
        for (int s = 0; s < 8; ++s) {
            a[0][s][0] = *(const float4*)(ap0 + s * 32);
            a[0][s][1] = *(const float4*)(ap0 + s * 32 + 4);
            a[1][s][0] = *(const float4*)(ap1 + s * 32);
            a[1][s][1] = *(const float4*)(ap1 + s * 32 + 4);
        }

        f32x4 acc[2][16] = {};
        #pragma unroll
        for (int s = 0; s < 8; ++s) {
            const bf16x8 fa0 = pack8(a[0][s][0], a[0][s][1]);
            const bf16x8 fa1 = pack8(a[1][s][0], a[1][s][1]);
            const int kb = laneq * 8 + s * 32;
            #pragma unroll
            for (int nt = 0; nt < 16; ++nt) {
                const int n = nt * 16 + lane15;
                const bf16x8 fb = *(const bf16x8*)(&sW[n * 256 + (kb ^ ((n & 7) << 3))]);
                acc[0][nt] = __builtin_amdgcn_mfma_f32_16x16x32_bf16(fa0, fb, acc[0][nt], 0, 0, 0);
                acc[1][nt] = __builtin_amdgcn_mfma_f32_16x16x32_bf16(fa1, fb, acc[1][nt], 0, 0, 0);
            }
        }

        // scatter-store to [cam][head][pix][32ch] bf16
        #pragma unroll
        for (int rt = 0; rt < 2; ++rt) {
            #pragma unroll
            for (int r = 0; r < 4; ++r) {
                const int row = rowbase + rt * 16 + laneq * 4 + r;
                const unsigned pix = ((unsigned)row * 43691u) >> 18;   // row/6
                const unsigned cam = (unsigned)row - pix * 6u;
                const unsigned base = (cam * 8u * FLEN + pix) * 32u;
                #pragma unroll
                for (int nt = 0; nt < 16; ++nt) {
                    const unsigned idx = base + (unsigned)(nt >> 1) * (FLEN * 32u)
                                       + (unsigned)((nt & 1) * 16 + lane15);
                    v_ws[idx] = f2bf(acc[rt][nt][r] + bcol[nt]);
                }
            }
        }
    }
}

// ---------------------------------------------------------------------------
// One launch:
//   blocks [0,256)    : W-stationary v-proj (1 block/CU, 128 KiB LDS)
//   blocks [256,456)  : (q+pos) @ Wso -> off_ws   (old verified gemm_body)
//   blocks [456,556)  : (q+pos) @ Waw -> aw_ws
//   block  556        : bev_mask format detect -> flag
// ---------------------------------------------------------------------------
__launch_bounds__(256, 1)
__global__ void fused_pre_gemm(const float* __restrict__ value,
                               const float* __restrict__ query,
                               const float* __restrict__ query_pos,
                               const float* __restrict__ Wv,  const float* __restrict__ bv,
                               const float* __restrict__ Wso, const float* __restrict__ bso,
                               const float* __restrict__ Waw, const float* __restrict__ baw,
                               const void* __restrict__ bm,
                               ushort* __restrict__ v_ws,
                               float* __restrict__ off_ws,
                               float* __restrict__ aw_ws,
                               int* __restrict__ flag) {
    __shared__ ushort sW[256 * 256];   // 128 KiB
    const int bid = blockIdx.x;
    if (bid < 256) {
        vproj_body(sW, value, Wv, bv, v_ws, bid);
    } else if (bid < 456) {
        const int r = bid - 256;
        gemm_body<1>(sW, sW + 128 * LSTRIDE, query, query_pos, Wso, 512, bso, nullptr,
                     off_ws, 512, NQ, r >> 2, r & 3);
    } else if (bid < 556) {
        const int r = bid - 456;
        gemm_body<1>(sW, sW + 128 * LSTRIDE, query, query_pos, Waw, 256, baw, nullptr,
                     aw_ws, 256, NQ, r >> 1, r & 1);
    } else {
        const int t = threadIdx.x;
        const uint4* p4 = (const uint4*)bm;
        unsigned acc = 0;
        for (int i = t; i < (CAMS * NQ * DEPTH) / 16; i += 256) {
            const uint4 w = p4[i];
            acc |= w.x | w.y | w.z | w.w;
        }
        #pragma unroll
        for (int off = 32; off >= 1; off >>= 1) acc |= __shfl_xor(acc, off);
        unsigned* sred = (unsigned*)sW;
        if ((t & 63) == 0) sred[t >> 6] = acc;
        __syncthreads();
        if (t == 0) {
            const unsigned a = sred[0] | sred[1] | sred[2] | sred[3];
            flag[0] = (a & 0xFFFFFF00u) ? 1 : 0;
        }
    }
}

__launch_bounds__(256)
__global__ void gemm_out_kernel(const float* __restrict__ slots,
                                const float* __restrict__ Wout,
                                const float* __restrict__ bout,
                                const float* __restrict__ query,
                                float* __restrict__ out) {
    __shared__ ushort sA[128 * LSTRIDE];
    __shared__ ushort sB[128 * LSTRIDE];
    const int bid = blockIdx.x;
    gemm_body<3>(sA, sB, slots, nullptr, Wout, 256, bout, query,
                 out, 256, NQ, bid >> 1, bid & 1);
}

// ---------------------------------------------------------------------------
// Deformable sampling — folds bev_mask decode, softmax, and 1/count scaling.
// v layout is [cam][head][pix][32ch] bf16 so bilinear x/x+1 corners are
// adjacent 64B chunks. Mask format via runtime flag (block-uniform branch).
// ---------------------------------------------------------------------------
__launch_bounds__(256)
__global__ void sample_kernel(const ushort* __restrict__ v,
                              const float* __restrict__ off_ws,
                              const float* __restrict__ aw_logit,
                              const float* __restrict__ rp,      // (CAMS,NQ,DEPTH,2)
                              const void* __restrict__ bm,
                              const int* __restrict__ flag,
                              float* __restrict__ slots) {
    const int q = blockIdx.x;
    const int t = threadIdx.x;
    const int h = t >> 5;
    const int e8 = (t >> 2) & 7;
    const int ch8 = (t & 3) * 8;
    const int l = e8 >> 1;
    const int ebase = h * 32 + e8 * 4;

    const int Wl = c_LW[l], Hl = c_LH[l], St = c_LS[l];
    const float fWl = (float)Wl, fHl = (float)Hl;

    const int fmt = *flag;
    int am = 0, cnt = 0;
    if (fmt == 1) {         // bool bytes: 4 bytes per (cam,q)
        #pragma unroll
        for (int cam = 0; cam < CAMS; ++cam) {
            const unsigned w = ((const unsigned*)bm)[cam * NQ + q];
            const int a = (w != 0u);
            am |= a << cam;
            cnt += a;
        }
    } else {                // int32: 16 bytes per (cam,q)
        #pragma unroll
        for (int cam = 0; cam < CAMS; ++cam) {
            const int4 w = ((const int4*)bm)[cam * NQ + q];
            const int a = ((w.x | w.y | w.z | w.w) != 0);
            am |= a << cam;
            cnt += a;
        }
    }
    const float invq = 1.0f / (float)(cnt > 0 ? cnt : 1);

    // softmax over the 32 (l,p) logits of this (q,h): lanes differing in e8
    const float4 lg = *(const float4*)(aw_logit + (size_t)q * 256 + ebase);
    float mx = fmaxf(fmaxf(lg.x, lg.y), fmaxf(lg.z, lg.w));
    mx = fmaxf(mx, __shfl_xor(mx, 4));
    mx = fmaxf(mx, __shfl_xor(mx, 8));
    mx = fmaxf(mx, __shfl_xor(mx, 16));
    const float e0 = expf(lg.x - mx), e1 = expf(lg.y - mx);
    const float e2 = expf(lg.z - mx), e3 = expf(lg.w - mx);
    float s = e0 + e1 + e2 + e3;
    s += __shfl_xor(s, 4);
    s += __shfl_xor(s, 8);
    s += __shfl_xor(s, 16);
    const float sc = invq / s;                 // fold 1/count into the weights
    const float awv[4] = {e0 * sc, e1 * sc, e2 * sc, e3 * sc};

    const float* ofp = off_ws + (size_t)q * 512 + ebase * 2;
    const float4 o01 = *(const float4*)(ofp);
    const float4 o23 = *(const float4*)(ofp + 4);
    const float offx[4] = {o01.x, o01.z, o23.x, o23.z};
    const float offy[4] = {o01.y, o01.w, o23.y, o23.w};

    float acc[8] = {};

    for (int cam = 0; cam < CAMS; ++cam) {
        if (!((am >> cam) & 1)) continue;   // uniform branch

        const int camhF = (cam * 8 + h) * FLEN + St;

        const float4 r01 = *(const float4*)(rp + (size_t)cam * (NQ * 8) + q * 8);
        const float4 r23 = *(const float4*)(rp + (size_t)cam * (NQ * 8) + q * 8 + 4);
        const float rx[4] = {r01.x, r01.z, r23.x, r23.z};
        const float ry[4] = {r01.y, r01.w, r23.y, r23.w};

        int   addr[16];
        float wgt[16];
        #pragma unroll
        for (int j = 0; j < 4; ++j) {
            const float x = fmaf(rx[j], fWl, offx[j]) - 0.5f;
            const float y = fmaf(ry[j], fHl, offy[j]) - 0.5f;
            const float x0f = floorf(x), y0f = floorf(y);
            const int x0 = (int)x0f, y0 = (int)y0f;
            const float fx = x - x0f, fy = y - y0f;
            const float wx0 = 1.f - fx, wy0 = 1.f - fy;
            #pragma unroll
            for (int c = 0; c < 4; ++c) {
                const int cx = x0 + (c & 1);
                const int cy = y0 + (c >> 1);
                const bool valid = ((unsigned)cx < (unsigned)Wl) & ((unsigned)cy < (unsigned)Hl);
                const int pixo = valid ? (cy * Wl + cx) : 0;
                addr[j * 4 + c] = ((camhF + pixo) << 5) + ch8;
                wgt[j * 4 + c] = valid
                    ? (((c & 1) ? fx : wx0) * ((c >> 1) ? fy : wy0) * awv[j])
                    : 0.f;
            }
        }
        #pragma unroll
        for (int i = 0; i < 16; ++i) {
            const uint4 u = *(const uint4*)(v + addr[i]);
            const float w = wgt[i];
            acc[0] = fmaf(w, bflo(u.x), acc[0]);
            acc[1] = fmaf(w, bfhi(u.x), acc[1]);
            acc[2] = fmaf(w, bflo(u.y), acc[2]);
            acc[3] = fmaf(w, bfhi(u.y), acc[3]);
            acc[4] = fmaf(w, bflo(u.z), acc[4]);
            acc[5] = fmaf(w, bfhi(u.z), acc[5]);
            acc[6] = fmaf(w, bflo(u.w), acc[6]);
            acc[7] = fmaf(w, bfhi(u.w), acc[7]);
        }
    }

    #pragma unroll
    for (int i = 0; i < 8; ++i) {
        acc[i] += __shfl_xor(acc[i], 4);
        acc[i] += __shfl_xor(acc[i], 8);
        acc[i] += __shfl_xor(acc[i], 16);
    }
    slots[(size_t)q * 256 + h * 32 + ch8 + e8] = acc[e8];
}

// ---------------------------------------------------------------------------
extern "C" void kernel_launch(void* const* d_in, const int* in_sizes, int n_in,
                              void* d_out, int out_size, void* d_ws, size_t ws_size,
                              hipStream_t stream) {
    const float* query     = (const float*)d_in[0];
    // d_in[1] = key (unused by reference)
    const float* value     = (const float*)d_in[2];
    const float* query_pos = (const float*)d_in[3];
    const float* refpts    = (const float*)d_in[4];
    const void*  bev_mask  = d_in[5];
    const float* Wv   = (const float*)d_in[8];
    const float* bv   = (const float*)d_in[9];
    const float* Wso  = (const float*)d_in[10];
    const float* bso  = (const float*)d_in[11];
    const float* Waw  = (const float*)d_in[12];
    const float* baw  = (const float*)d_in[13];
    const float* Wout = (const float*)d_in[14];
    const float* bout = (const float*)d_in[15];
    float* out = (float*)d_out;

    // Workspace layout
    ushort* v_ws  = (ushort*)d_ws;                       // MV*256 bf16 = 45.96 MB
    float* off_ws = (float*)(v_ws + (size_t)MV * 256);   // NQ*512 fp32
    float* aw_ws  = off_ws + (size_t)NQ * 512;           // NQ*256 (raw logits)
    float* slots  = aw_ws + (size_t)NQ * 256;            // NQ*256
    int*   flag   = (int*)(slots + (size_t)NQ * 256);    // 1 int

    // v-proj (W-stationary) + q-projections + mask detect, one dispatch
    hipLaunchKernelGGL(fused_pre_gemm, dim3(557), dim3(256), 0, stream,
                       value, query, query_pos, Wv, bv, Wso, bso, Waw, baw,
                       bev_mask, v_ws, off_ws, aw_ws, flag);

    // deformable sampling (mask decode + softmax + 1/count folded in)
    hipLaunchKernelGGL(sample_kernel, dim3(NQ), dim3(256), 0, stream,
                       v_ws, off_ws, aw_ws, refpts, bev_mask, flag, slots);

    // out = slots @ Wout + bout + query   (1/count already folded into sample)
    hipLaunchKernelGGL(gemm_out_kernel, dim3(100), dim3(256), 0, stream,
                       slots, Wout, bout, query, out);
}